// Round 1
// baseline (297.090 us; speedup 1.0000x reference)
//
#include <hip/hip_runtime.h>

#define NTOK 2048
#define HID 4096
#define NOUT 4096
#define NLORA 16
#define RANK 16

typedef float floatx4 __attribute__((ext_vector_type(4)));
typedef __bf16 bf16x8 __attribute__((ext_vector_type(8)));

__device__ __forceinline__ unsigned short f2b(float f) {
  unsigned int u = __float_as_uint(f);
  u += 0x7FFFu + ((u >> 16) & 1u);   // round-to-nearest-even
  return (unsigned short)(u >> 16);
}
__device__ __forceinline__ float b2f(unsigned short u) {
  return __uint_as_float(((unsigned int)u) << 16);
}

// async global->LDS, 16 bytes per lane; LDS dest is wave-uniform base + lane*16
__device__ __forceinline__ void gld16(const char* g, char* l) {
  __builtin_amdgcn_global_load_lds(
      (const __attribute__((address_space(1))) unsigned int*)g,
      (__attribute__((address_space(3))) unsigned int*)l,
      16, 0, 0);
}

// ---------------- runtime dtype detection ----------------
// flags[0]: 1 = float tensors are bf16 in memory, 0 = fp32
// flags[1]: 1 = indices are int64, 0 = int32
__global__ void detect_kernel(const unsigned short* __restrict__ xraw,
                              const int* __restrict__ idxraw,
                              int* __restrict__ flags) {
  if (threadIdx.x == 0 && blockIdx.x == 0) {
    // If x were fp32, even uint16s are low mantissa halves -> bf16-exponent
    // uniform random; genuine bf16 N(0,1) data has exponent in ~[96,159].
    int wild = 0;
    for (int i = 0; i < 64; i += 2) {
      int e = (xraw[i] >> 7) & 0xFF;
      if (e < 96 || e > 159) wild = 1;
    }
    flags[0] = wild ? 0 : 1;
    // int64 indices in [0,16): every odd int32 word is 0.
    int nzodd = 0;
    for (int i = 1; i < 64; i += 2) nzodd |= (idxraw[i] != 0) ? 1 : 0;
    flags[1] = nzodd ? 0 : 1;
  }
}

// ---------------- fp32 -> bf16 normalize (no-op when already bf16) --------
__global__ __launch_bounds__(256) void norm_kernel(const float* __restrict__ src,
                                                   unsigned short* __restrict__ dst,
                                                   const int* __restrict__ flags) {
  if (flags[0]) return;  // raw buffers already bf16; GEMM reads them directly
  const int i = blockIdx.x * 256 + threadIdx.x;   // 8 elements per thread
  const float4 a = ((const float4*)src)[2 * i];
  const float4 b = ((const float4*)src)[2 * i + 1];
  union { unsigned short us[8]; uint4 v; } p;
  p.us[0] = f2b(a.x); p.us[1] = f2b(a.y); p.us[2] = f2b(a.z); p.us[3] = f2b(a.w);
  p.us[4] = f2b(b.x); p.us[5] = f2b(b.y); p.us[6] = f2b(b.z); p.us[7] = f2b(b.w);
  ((uint4*)dst)[i] = p.v;
}

// ---------------- per-token ax[t][r] = A[idx_t][r] . x_t ------------------
__global__ __launch_bounds__(256) void ax_kernel(const void* __restrict__ xv,
                                                 const void* __restrict__ lav,
                                                 const int* __restrict__ idxraw,
                                                 const int* __restrict__ flags,
                                                 float* __restrict__ axo,
                                                 int* __restrict__ tok) {
  const int t = blockIdx.x;
  const int tid = threadIdx.x;
  const int wave = tid >> 6, lane = tid & 63;
  const int isb = flags[0];
  const int l = flags[1] ? idxraw[2 * t] : idxraw[t];
  if (tid == 0) tok[t] = (l >= 0 && l < NLORA) ? l : -1;
  if (l < 0 || l >= NLORA) {
    if (tid < RANK) axo[t * RANK + tid] = 0.f;
    return;
  }
  float s0 = 0.f, s1 = 0.f, s2 = 0.f, s3 = 0.f;
  if (isb) {
    const unsigned short* xr = (const unsigned short*)xv + (size_t)t * HID;
    const unsigned short* Ab = (const unsigned short*)lav + ((size_t)l * RANK + wave * 4) * HID;
    #pragma unroll 4
    for (int i = 0; i < HID / 256; ++i) {
      const int h = (i * 64 + lane) * 4;
      const ushort4 u = *(const ushort4*)(xr + h);
      const float x0 = b2f(u.x), x1 = b2f(u.y), x2 = b2f(u.z), x3 = b2f(u.w);
      const ushort4 a0 = *(const ushort4*)(Ab + 0 * HID + h);
      const ushort4 a1 = *(const ushort4*)(Ab + 1 * HID + h);
      const ushort4 a2 = *(const ushort4*)(Ab + 2 * HID + h);
      const ushort4 a3 = *(const ushort4*)(Ab + 3 * HID + h);
      s0 += b2f(a0.x) * x0 + b2f(a0.y) * x1 + b2f(a0.z) * x2 + b2f(a0.w) * x3;
      s1 += b2f(a1.x) * x0 + b2f(a1.y) * x1 + b2f(a1.z) * x2 + b2f(a1.w) * x3;
      s2 += b2f(a2.x) * x0 + b2f(a2.y) * x1 + b2f(a2.z) * x2 + b2f(a2.w) * x3;
      s3 += b2f(a3.x) * x0 + b2f(a3.y) * x1 + b2f(a3.z) * x2 + b2f(a3.w) * x3;
    }
  } else {
    const float* xr = (const float*)xv + (size_t)t * HID;
    const float* Ab = (const float*)lav + ((size_t)l * RANK + wave * 4) * HID;
    #pragma unroll 4
    for (int i = 0; i < HID / 256; ++i) {
      const int h = (i * 64 + lane) * 4;
      const float4 x4 = *(const float4*)(xr + h);
      const float4 a0 = *(const float4*)(Ab + 0 * HID + h);
      const float4 a1 = *(const float4*)(Ab + 1 * HID + h);
      const float4 a2 = *(const float4*)(Ab + 2 * HID + h);
      const float4 a3 = *(const float4*)(Ab + 3 * HID + h);
      s0 += a0.x * x4.x + a0.y * x4.y + a0.z * x4.z + a0.w * x4.w;
      s1 += a1.x * x4.x + a1.y * x4.y + a1.z * x4.z + a1.w * x4.w;
      s2 += a2.x * x4.x + a2.y * x4.y + a2.z * x4.z + a2.w * x4.w;
      s3 += a3.x * x4.x + a3.y * x4.y + a3.z * x4.z + a3.w * x4.w;
    }
  }
  #pragma unroll
  for (int off = 32; off; off >>= 1) {
    s0 += __shfl_xor(s0, off, 64);
    s1 += __shfl_xor(s1, off, 64);
    s2 += __shfl_xor(s2, off, 64);
    s3 += __shfl_xor(s3, off, 64);
  }
  if (lane == 0) {
    axo[t * RANK + wave * 4 + 0] = s0;
    axo[t * RANK + wave * 4 + 1] = s1;
    axo[t * RANK + wave * 4 + 2] = s2;
    axo[t * RANK + wave * 4 + 3] = s3;
  }
}

// load 16 consecutive floats (fp32 or bf16 storage) into dst[16]
__device__ __forceinline__ void load16(const void* base, int isb, size_t elem_off,
                                       float* dst) {
  if (isb) {
    const ushort4* p = (const ushort4*)((const unsigned short*)base + elem_off);
    #pragma unroll
    for (int g = 0; g < 4; ++g) {
      const ushort4 q = p[g];
      dst[4 * g + 0] = b2f(q.x); dst[4 * g + 1] = b2f(q.y);
      dst[4 * g + 2] = b2f(q.z); dst[4 * g + 3] = b2f(q.w);
    }
  } else {
    const float4* p = (const float4*)((const float*)base + elem_off);
    #pragma unroll
    for (int g = 0; g < 4; ++g) {
      const float4 q = p[g];
      dst[4 * g + 0] = q.x; dst[4 * g + 1] = q.y;
      dst[4 * g + 2] = q.z; dst[4 * g + 3] = q.w;
    }
  }
}

// ---------------- main GEMM (+ fused bias & LoRA-B epilogue) --------------
// 128x128 tile, BK=32, 4 waves (2x2), 16x16x32 bf16 MFMA, global_load_lds.
__global__ __launch_bounds__(256) void gemm_kernel(
    const void* __restrict__ x_raw, const void* __restrict__ w_raw,
    const unsigned short* __restrict__ xb_ws, const unsigned short* __restrict__ wb_ws,
    const void* __restrict__ bias_raw, const void* __restrict__ lorab_raw,
    const float* __restrict__ axv, const int* __restrict__ tok,
    const int* __restrict__ flags, void* __restrict__ outv) {
  __shared__ unsigned short As[128 * 32];
  __shared__ unsigned short Bs[128 * 32];
  const int isb = flags[0];
  const unsigned short* Xb = isb ? (const unsigned short*)x_raw : xb_ws;
  const unsigned short* Wb = isb ? (const unsigned short*)w_raw : wb_ws;

  const int tid = threadIdx.x;
  const int wave = tid >> 6;
  const int lane = tid & 63;
  const int t0 = blockIdx.y * 128;
  const int o0 = blockIdx.x * 128;
  const int wr = (wave >> 1) * 64;
  const int wc = (wave & 1) * 64;

  // staging: tile flat byte = m*64 + kbyte; per wave-issue 1 KiB, 2 issues/tile
  const int fb0 = wave * 1024 + lane * 16;
  const int fb1 = fb0 + 4096;
  const char* gA0 = (const char*)Xb + (size_t)(t0 + (fb0 >> 6)) * (HID * 2) + (fb0 & 63);
  const char* gA1 = (const char*)Xb + (size_t)(t0 + (fb1 >> 6)) * (HID * 2) + (fb1 & 63);
  const char* gB0 = (const char*)Wb + (size_t)(o0 + (fb0 >> 6)) * (HID * 2) + (fb0 & 63);
  const char* gB1 = (const char*)Wb + (size_t)(o0 + (fb1 >> 6)) * (HID * 2) + (fb1 & 63);
  char* lA0 = (char*)As + wave * 1024;
  char* lA1 = (char*)As + 4096 + wave * 1024;
  char* lB0 = (char*)Bs + wave * 1024;
  char* lB1 = (char*)Bs + 4096 + wave * 1024;

  const int fm = lane & 15;             // A row / B col within 16-tile
  const int fkb = (lane >> 4) * 16;     // k fragment byte offset (8 bf16)

  floatx4 acc[4][4];
  #pragma unroll
  for (int i = 0; i < 4; ++i)
    #pragma unroll
    for (int j = 0; j < 4; ++j)
      acc[i][j] = (floatx4){0.f, 0.f, 0.f, 0.f};

  for (int kb = 0; kb < HID * 2; kb += 64) {   // 64 bytes = BK=32 bf16
    gld16(gA0 + kb, lA0);
    gld16(gA1 + kb, lA1);
    gld16(gB0 + kb, lB0);
    gld16(gB1 + kb, lB1);
    __syncthreads();
    bf16x8 af[4], bfr[4];
    #pragma unroll
    for (int i = 0; i < 4; ++i) {
      af[i]  = *(const bf16x8*)((const char*)As + (wr + i * 16 + fm) * 64 + fkb);
      bfr[i] = *(const bf16x8*)((const char*)Bs + (wc + i * 16 + fm) * 64 + fkb);
    }
    #pragma unroll
    for (int i = 0; i < 4; ++i)
      #pragma unroll
      for (int j = 0; j < 4; ++j)
        acc[i][j] = __builtin_amdgcn_mfma_f32_16x16x32_bf16(af[i], bfr[j], acc[i][j], 0, 0, 0);
    __syncthreads();
  }

  // epilogue: C/D layout col=lane&15, row=(lane>>4)*4+reg
  const int c = lane & 15;
  const int rr = (lane >> 4) * 4;
  float bv[4];
  #pragma unroll
  for (int j = 0; j < 4; ++j) {
    const int o = o0 + wc + j * 16 + c;
    bv[j] = isb ? b2f(((const unsigned short*)bias_raw)[o]) : ((const float*)bias_raw)[o];
  }
  unsigned short* outb = (unsigned short*)outv;
  float* outf = (float*)outv;
  #pragma unroll
  for (int mi = 0; mi < 4; ++mi) {
    #pragma unroll
    for (int r = 0; r < 4; ++r) {
      const int t = t0 + wr + mi * 16 + rr + r;
      const int l = tok[t];
      float axr[16];
      if (l >= 0) {
        const float4* ap = (const float4*)(axv + t * RANK);
        #pragma unroll
        for (int g = 0; g < 4; ++g) {
          const float4 q = ap[g];
          axr[4 * g] = q.x; axr[4 * g + 1] = q.y; axr[4 * g + 2] = q.z; axr[4 * g + 3] = q.w;
        }
      }
      #pragma unroll
      for (int j = 0; j < 4; ++j) {
        const int o = o0 + wc + j * 16 + c;
        float v = acc[mi][j][r] + bv[j];
        if (l >= 0) {
          float brow[16];
          load16(lorab_raw, isb, ((size_t)l * NOUT + o) * RANK, brow);
          float d = 0.f;
          #pragma unroll
          for (int g = 0; g < 16; ++g) d += brow[g] * axr[g];
          v += d;
        }
        const size_t oi = (size_t)t * NOUT + o;
        if (isb) outb[oi] = f2b(v); else outf[oi] = v;
      }
    }
  }
}

extern "C" void kernel_launch(void* const* d_in, const int* in_sizes, int n_in,
                              void* d_out, int out_size, void* d_ws, size_t ws_size,
                              hipStream_t stream) {
  const void* x  = d_in[0];
  const void* w  = d_in[1];
  const void* bs = d_in[2];
  const void* la = d_in[3];
  const void* lb = d_in[4];
  const int*  ix = (const int*)d_in[5];

  const size_t xb_bytes  = (size_t)NTOK * HID * 2;
  const size_t wb_bytes  = (size_t)NOUT * HID * 2;
  const size_t ax_bytes  = (size_t)NTOK * RANK * 4;
  const size_t tok_bytes = (size_t)NTOK * 4;
  const size_t full_need = xb_bytes + wb_bytes + ax_bytes + tok_bytes + 64;

  char* ws = (char*)d_ws;
  unsigned short *xb, *wb2;
  float* axp; int* tok; int* flags;
  const bool full = ws_size >= full_need;
  if (full) {
    xb    = (unsigned short*)ws;
    wb2   = (unsigned short*)(ws + xb_bytes);
    axp   = (float*)(ws + xb_bytes + wb_bytes);
    tok   = (int*)(ws + xb_bytes + wb_bytes + ax_bytes);
    flags = (int*)(ws + xb_bytes + wb_bytes + ax_bytes + tok_bytes);
  } else {
    axp   = (float*)ws;
    tok   = (int*)(ws + ax_bytes);
    flags = (int*)(ws + ax_bytes + tok_bytes);
    xb    = (unsigned short*)x;   // small-ws fallback: assume raw already bf16
    wb2   = (unsigned short*)w;
  }

  detect_kernel<<<1, 64, 0, stream>>>((const unsigned short*)x, ix, flags);
  if (full) {
    norm_kernel<<<(NTOK * HID / 8) / 256, 256, 0, stream>>>((const float*)x, xb, flags);
    norm_kernel<<<(NOUT * HID / 8) / 256, 256, 0, stream>>>((const float*)w, wb2, flags);
  }
  ax_kernel<<<NTOK, 256, 0, stream>>>(x, la, ix, flags, axp, tok);
  gemm_kernel<<<dim3(NOUT / 128, NTOK / 128), 256, 0, stream>>>(
      x, w, xb, wb2, bs, lb, axp, tok, flags, d_out);
}

// Round 2
// 287.150 us; speedup vs baseline: 1.0346x; 1.0346x over previous
//
#include <hip/hip_runtime.h>

#define NTOK 2048
#define HID 4096
#define NOUT 4096
#define NLORA 16
#define RANK 16

typedef float floatx4 __attribute__((ext_vector_type(4)));
typedef __bf16 bf16x8 __attribute__((ext_vector_type(8)));

__device__ __forceinline__ unsigned short f2b(float f) {
  unsigned int u = __float_as_uint(f);
  u += 0x7FFFu + ((u >> 16) & 1u);   // round-to-nearest-even
  return (unsigned short)(u >> 16);
}
__device__ __forceinline__ float b2f(unsigned short u) {
  return __uint_as_float(((unsigned int)u) << 16);
}

// async global->LDS, 16 bytes per lane; LDS dest is wave-uniform base + lane*16
__device__ __forceinline__ void gld16(const char* g, char* l) {
  __builtin_amdgcn_global_load_lds(
      (const __attribute__((address_space(1))) unsigned int*)g,
      (__attribute__((address_space(3))) unsigned int*)l,
      16, 0, 0);
}

// ---- inline per-wave dtype detection (no separate kernel, no flags buffer) --
// bf16 N(0,1) data: bf16-exponent of every sample in [96,159]. fp32 buffer's
// even uint16s are mantissa halves -> uniform exponents; P(all 64 in range)
// = 4^-64. Wave-uniform via ballot.
__device__ __forceinline__ int detect_bf16(const void* xraw) {
  const int lane = threadIdx.x & 63;
  const int e = (((const unsigned short*)xraw)[2 * lane] >> 7) & 0xFF;
  const unsigned long long wild = __ballot(e < 96 || e > 159);
  return wild == 0ull;
}
// int64 indices in [-1,16): every odd int32 word is 0 or -1-sign ext... for
// values >=0 odd words are 0; for int32 buffer odd words are other indices
// (P(all 32 odd words ==0) = 16^-32).
__device__ __forceinline__ int detect_i64(const int* idxraw) {
  const int lane = threadIdx.x & 63;
  const unsigned long long nz = __ballot((lane & 1) && idxraw[lane] != 0);
  return nz == 0ull;
}

// ---------------- fp32 -> bf16 normalize (merged x+w, no-op when bf16) -----
__global__ __launch_bounds__(256) void norm_kernel(const float* __restrict__ x,
                                                   const float* __restrict__ w,
                                                   unsigned short* __restrict__ xb,
                                                   unsigned short* __restrict__ wb) {
  if (detect_bf16(x)) return;   // raw buffers already bf16
  const int XN8 = NTOK * HID / 8;
  const int TOT8 = XN8 + NOUT * HID / 8;
  for (int i = blockIdx.x * 256 + threadIdx.x; i < TOT8; i += 2048 * 256) {
    const float* s; unsigned short* d; int j;
    if (i < XN8) { s = x; d = xb; j = i; } else { s = w; d = wb; j = i - XN8; }
    const float4 a = ((const float4*)s)[2 * j];
    const float4 b = ((const float4*)s)[2 * j + 1];
    union { unsigned short us[8]; uint4 v; } p;
    p.us[0] = f2b(a.x); p.us[1] = f2b(a.y); p.us[2] = f2b(a.z); p.us[3] = f2b(a.w);
    p.us[4] = f2b(b.x); p.us[5] = f2b(b.y); p.us[6] = f2b(b.z); p.us[7] = f2b(b.w);
    ((uint4*)d)[j] = p.v;
  }
}

// ---------------- per-token ax[t][r] = A[idx_t][r] . x_t ------------------
__global__ __launch_bounds__(256) void ax_kernel(const void* __restrict__ xv,
                                                 const void* __restrict__ lav,
                                                 const int* __restrict__ idxraw,
                                                 float* __restrict__ axo,
                                                 int* __restrict__ tok) {
  const int t = blockIdx.x;
  const int tid = threadIdx.x;
  const int wave = tid >> 6, lane = tid & 63;
  const int isb = detect_bf16(xv);
  const int l = detect_i64(idxraw) ? idxraw[2 * t] : idxraw[t];
  if (tid == 0) tok[t] = (l >= 0 && l < NLORA) ? l : -1;
  if (l < 0 || l >= NLORA) {
    if (tid < RANK) axo[t * RANK + tid] = 0.f;
    return;
  }
  float s0 = 0.f, s1 = 0.f, s2 = 0.f, s3 = 0.f;
  if (isb) {
    const unsigned short* xr = (const unsigned short*)xv + (size_t)t * HID;
    const unsigned short* Ab = (const unsigned short*)lav + ((size_t)l * RANK + wave * 4) * HID;
    #pragma unroll 4
    for (int i = 0; i < HID / 256; ++i) {
      const int h = (i * 64 + lane) * 4;
      const ushort4 u = *(const ushort4*)(xr + h);
      const float x0 = b2f(u.x), x1 = b2f(u.y), x2 = b2f(u.z), x3 = b2f(u.w);
      const ushort4 a0 = *(const ushort4*)(Ab + 0 * HID + h);
      const ushort4 a1 = *(const ushort4*)(Ab + 1 * HID + h);
      const ushort4 a2 = *(const ushort4*)(Ab + 2 * HID + h);
      const ushort4 a3 = *(const ushort4*)(Ab + 3 * HID + h);
      s0 += b2f(a0.x) * x0 + b2f(a0.y) * x1 + b2f(a0.z) * x2 + b2f(a0.w) * x3;
      s1 += b2f(a1.x) * x0 + b2f(a1.y) * x1 + b2f(a1.z) * x2 + b2f(a1.w) * x3;
      s2 += b2f(a2.x) * x0 + b2f(a2.y) * x1 + b2f(a2.z) * x2 + b2f(a2.w) * x3;
      s3 += b2f(a3.x) * x0 + b2f(a3.y) * x1 + b2f(a3.z) * x2 + b2f(a3.w) * x3;
    }
  } else {
    const float* xr = (const float*)xv + (size_t)t * HID;
    const float* Ab = (const float*)lav + ((size_t)l * RANK + wave * 4) * HID;
    #pragma unroll 4
    for (int i = 0; i < HID / 256; ++i) {
      const int h = (i * 64 + lane) * 4;
      const float4 x4 = *(const float4*)(xr + h);
      const float4 a0 = *(const float4*)(Ab + 0 * HID + h);
      const float4 a1 = *(const float4*)(Ab + 1 * HID + h);
      const float4 a2 = *(const float4*)(Ab + 2 * HID + h);
      const float4 a3 = *(const float4*)(Ab + 3 * HID + h);
      s0 += a0.x * x4.x + a0.y * x4.y + a0.z * x4.z + a0.w * x4.w;
      s1 += a1.x * x4.x + a1.y * x4.y + a1.z * x4.z + a1.w * x4.w;
      s2 += a2.x * x4.x + a2.y * x4.y + a2.z * x4.z + a2.w * x4.w;
      s3 += a3.x * x4.x + a3.y * x4.y + a3.z * x4.z + a3.w * x4.w;
    }
  }
  #pragma unroll
  for (int off = 32; off; off >>= 1) {
    s0 += __shfl_xor(s0, off, 64);
    s1 += __shfl_xor(s1, off, 64);
    s2 += __shfl_xor(s2, off, 64);
    s3 += __shfl_xor(s3, off, 64);
  }
  if (lane == 0) {
    axo[t * RANK + wave * 4 + 0] = s0;
    axo[t * RANK + wave * 4 + 1] = s1;
    axo[t * RANK + wave * 4 + 2] = s2;
    axo[t * RANK + wave * 4 + 3] = s3;
  }
}

// load 16 consecutive floats (fp32 or bf16 storage) into dst[16]
__device__ __forceinline__ void load16(const void* base, int isb, size_t elem_off,
                                       float* dst) {
  if (isb) {
    const ushort4* p = (const ushort4*)((const unsigned short*)base + elem_off);
    #pragma unroll
    for (int g = 0; g < 4; ++g) {
      const ushort4 q = p[g];
      dst[4 * g + 0] = b2f(q.x); dst[4 * g + 1] = b2f(q.y);
      dst[4 * g + 2] = b2f(q.z); dst[4 * g + 3] = b2f(q.w);
    }
  } else {
    const float4* p = (const float4*)((const float*)base + elem_off);
    #pragma unroll
    for (int g = 0; g < 4; ++g) {
      const float4 q = p[g];
      dst[4 * g + 0] = q.x; dst[4 * g + 1] = q.y;
      dst[4 * g + 2] = q.z; dst[4 * g + 3] = q.w;
    }
  }
}

// ---------------- main GEMM (+ fused bias & LoRA-B epilogue) --------------
// 128x128 tile, BK=32, 8 waves (4x2 grid, 32x64 per wave), 16x16x32 bf16
// MFMA, global_load_lds staging, bank-swizzled LDS granules.
// LDS granule g (16 B) holds tile (row = g>>2, kgroup q where
// (g&3) = q ^ ((row>>1)&3)) -> rows map to 8 bank groups, 2-way aliasing.
__global__ __launch_bounds__(512, 4) void gemm_kernel(
    const void* __restrict__ x_raw, const void* __restrict__ w_raw,
    const unsigned short* __restrict__ xb_ws, const unsigned short* __restrict__ wb_ws,
    const void* __restrict__ bias_raw, const void* __restrict__ lorab_raw,
    const float* __restrict__ axv, const int* __restrict__ tok,
    void* __restrict__ outv) {
  __shared__ unsigned short As[128 * 32];
  __shared__ unsigned short Bs[128 * 32];
  const int isb = detect_bf16(x_raw);
  const unsigned short* Xb = isb ? (const unsigned short*)x_raw : xb_ws;
  const unsigned short* Wb = isb ? (const unsigned short*)w_raw : wb_ws;

  const int tid = threadIdx.x;
  const int wave = tid >> 6;
  const int lane = tid & 63;
  const int t0 = blockIdx.y * 128;
  const int o0 = blockIdx.x * 128;
  const int wr = (wave >> 1) * 32;      // 4 row-groups of 32
  const int wc = (wave & 1) * 64;       // 2 col-groups of 64

  // staging: granule g = wave*64 + lane covers the full 8 KB tile per issue
  const int sg = wave * 64 + lane;
  const int srow = sg >> 2;
  const int sq = (sg & 3) ^ ((srow >> 1) & 3);     // swizzled k-group
  const char* gA = (const char*)Xb + (size_t)(t0 + srow) * (HID * 2) + sq * 16;
  const char* gB = (const char*)Wb + (size_t)(o0 + srow) * (HID * 2) + sq * 16;
  char* lA = (char*)As + wave * 1024;
  char* lB = (char*)Bs + wave * 1024;

  const int fm = lane & 15;             // row within 16-tile
  const int fq = lane >> 4;             // k-group 0..3 (8 bf16 each)

  floatx4 acc[2][4];
  #pragma unroll
  for (int i = 0; i < 2; ++i)
    #pragma unroll
    for (int j = 0; j < 4; ++j)
      acc[i][j] = (floatx4){0.f, 0.f, 0.f, 0.f};

  // loop-invariant swizzled LDS read addresses
  const char* aAddr[2]; const char* bAddr[4];
  #pragma unroll
  for (int i = 0; i < 2; ++i) {
    const int r = wr + i * 16 + fm;
    aAddr[i] = (const char*)As + (r * 4 + (fq ^ ((r >> 1) & 3))) * 16;
  }
  #pragma unroll
  for (int j = 0; j < 4; ++j) {
    const int r = wc + j * 16 + fm;
    bAddr[j] = (const char*)Bs + (r * 4 + (fq ^ ((r >> 1) & 3))) * 16;
  }

  for (int kb = 0; kb < HID * 2; kb += 64) {   // 64 bytes = BK=32 bf16
    gld16(gA + kb, lA);
    gld16(gB + kb, lB);
    __syncthreads();
    bf16x8 af[2], bfr[4];
    #pragma unroll
    for (int i = 0; i < 2; ++i) af[i] = *(const bf16x8*)aAddr[i];
    #pragma unroll
    for (int j = 0; j < 4; ++j) bfr[j] = *(const bf16x8*)bAddr[j];
    #pragma unroll
    for (int i = 0; i < 2; ++i)
      #pragma unroll
      for (int j = 0; j < 4; ++j)
        acc[i][j] = __builtin_amdgcn_mfma_f32_16x16x32_bf16(af[i], bfr[j], acc[i][j], 0, 0, 0);
    __syncthreads();
  }

  // epilogue: C/D layout col=lane&15, row=(lane>>4)*4+reg
  const int c = lane & 15;
  const int rr = (lane >> 4) * 4;
  float bv[4];
  #pragma unroll
  for (int j = 0; j < 4; ++j) {
    const int o = o0 + wc + j * 16 + c;
    bv[j] = isb ? b2f(((const unsigned short*)bias_raw)[o]) : ((const float*)bias_raw)[o];
  }
  unsigned short* outb = (unsigned short*)outv;
  float* outf = (float*)outv;
  #pragma unroll
  for (int mi = 0; mi < 2; ++mi) {
    #pragma unroll
    for (int r = 0; r < 4; ++r) {
      const int t = t0 + wr + mi * 16 + rr + r;
      const int l = tok[t];
      float axr[16];
      if (l >= 0) {
        const float4* ap = (const float4*)(axv + t * RANK);
        #pragma unroll
        for (int g = 0; g < 4; ++g) {
          const float4 q = ap[g];
          axr[4 * g] = q.x; axr[4 * g + 1] = q.y; axr[4 * g + 2] = q.z; axr[4 * g + 3] = q.w;
        }
      }
      #pragma unroll
      for (int j = 0; j < 4; ++j) {
        const int o = o0 + wc + j * 16 + c;
        float v = acc[mi][j][r] + bv[j];
        if (l >= 0) {
          float brow[16];
          load16(lorab_raw, isb, ((size_t)l * NOUT + o) * RANK, brow);
          float d = 0.f;
          #pragma unroll
          for (int g = 0; g < 16; ++g) d += brow[g] * axr[g];
          v += d;
        }
        const size_t oi = (size_t)t * NOUT + o;
        if (isb) outb[oi] = f2b(v); else outf[oi] = v;
      }
    }
  }
}

extern "C" void kernel_launch(void* const* d_in, const int* in_sizes, int n_in,
                              void* d_out, int out_size, void* d_ws, size_t ws_size,
                              hipStream_t stream) {
  const void* x  = d_in[0];
  const void* w  = d_in[1];
  const void* bs = d_in[2];
  const void* la = d_in[3];
  const void* lb = d_in[4];
  const int*  ix = (const int*)d_in[5];

  const size_t xb_bytes  = (size_t)NTOK * HID * 2;
  const size_t wb_bytes  = (size_t)NOUT * HID * 2;
  const size_t ax_bytes  = (size_t)NTOK * RANK * 4;
  const size_t tok_bytes = (size_t)NTOK * 4;
  const size_t full_need = xb_bytes + wb_bytes + ax_bytes + tok_bytes + 64;

  char* ws = (char*)d_ws;
  unsigned short *xb, *wb2;
  float* axp; int* tok;
  const bool full = ws_size >= full_need;
  if (full) {
    xb    = (unsigned short*)ws;
    wb2   = (unsigned short*)(ws + xb_bytes);
    axp   = (float*)(ws + xb_bytes + wb_bytes);
    tok   = (int*)(ws + xb_bytes + wb_bytes + ax_bytes);
  } else {
    axp   = (float*)ws;
    tok   = (int*)(ws + ax_bytes);
    xb    = (unsigned short*)x;   // small-ws fallback: assume raw already bf16
    wb2   = (unsigned short*)w;
  }

  if (full) {
    norm_kernel<<<2048, 256, 0, stream>>>((const float*)x, (const float*)w, xb, wb2);
  }
  ax_kernel<<<NTOK, 256, 0, stream>>>(x, la, ix, axp, tok);
  gemm_kernel<<<dim3(NOUT / 128, NTOK / 128), 512, 0, stream>>>(
      x, w, xb, wb2, bs, lb, axp, tok, d_out);
}

// Round 3
// 271.370 us; speedup vs baseline: 1.0948x; 1.0581x over previous
//
#include <hip/hip_runtime.h>

#define NTOK 2048
#define HID 4096
#define NOUT 4096
#define NLORA 16
#define RANK 16

typedef float floatx4 __attribute__((ext_vector_type(4)));
typedef __bf16 bf16x8 __attribute__((ext_vector_type(8)));

__device__ __forceinline__ unsigned short f2b(float f) {
  unsigned int u = __float_as_uint(f);
  u += 0x7FFFu + ((u >> 16) & 1u);   // round-to-nearest-even
  return (unsigned short)(u >> 16);
}
__device__ __forceinline__ float b2f(unsigned short u) {
  return __uint_as_float(((unsigned int)u) << 16);
}

// async global->LDS, 16 bytes per lane; LDS dest is wave-uniform base + lane*16
__device__ __forceinline__ void gld16(const char* g, char* l) {
  __builtin_amdgcn_global_load_lds(
      (const __attribute__((address_space(1))) unsigned int*)g,
      (__attribute__((address_space(3))) unsigned int*)l,
      16, 0, 0);
}

// ---- inline per-wave dtype detection ----
__device__ __forceinline__ int detect_bf16(const void* xraw) {
  const int lane = threadIdx.x & 63;
  const int e = (((const unsigned short*)xraw)[2 * lane] >> 7) & 0xFF;
  const unsigned long long wild = __ballot(e < 96 || e > 159);
  return wild == 0ull;
}
__device__ __forceinline__ int detect_i64(const int* idxraw) {
  const int lane = threadIdx.x & 63;
  const unsigned long long nz = __ballot((lane & 1) && idxraw[lane] != 0);
  return nz == 0ull;
}

// -------- prep: blocks [0,2048) = per-token ax; blocks [2048,2560) = norm ---
__global__ __launch_bounds__(256) void prep_kernel(
    const void* __restrict__ xv, const void* __restrict__ wv,
    const void* __restrict__ lav, const int* __restrict__ idxraw,
    unsigned short* __restrict__ xb, unsigned short* __restrict__ wb,
    float* __restrict__ axo, int* __restrict__ tok, int do_norm) {
  const int tid = threadIdx.x;
  if (blockIdx.x >= NTOK) {
    // fp32 -> bf16 conversion of x and w (no-op when inputs already bf16)
    if (detect_bf16(xv) || !do_norm) return;
    const int XN8 = NTOK * HID / 8;
    const int TOT8 = XN8 + NOUT * HID / 8;
    for (int i = (blockIdx.x - NTOK) * 256 + tid; i < TOT8; i += 512 * 256) {
      const float* s; unsigned short* d; int j;
      if (i < XN8) { s = (const float*)xv; d = xb; j = i; }
      else { s = (const float*)wv; d = wb; j = i - XN8; }
      const float4 a = ((const float4*)s)[2 * j];
      const float4 b = ((const float4*)s)[2 * j + 1];
      union { unsigned short us[8]; uint4 v; } p;
      p.us[0] = f2b(a.x); p.us[1] = f2b(a.y); p.us[2] = f2b(a.z); p.us[3] = f2b(a.w);
      p.us[4] = f2b(b.x); p.us[5] = f2b(b.y); p.us[6] = f2b(b.z); p.us[7] = f2b(b.w);
      ((uint4*)d)[j] = p.v;
    }
    return;
  }
  // ---- ax part: ax[t][r] = A[idx_t][r] . x_t ----
  const int t = blockIdx.x;
  const int wave = tid >> 6, lane = tid & 63;
  const int isb = detect_bf16(xv);
  const int l = detect_i64(idxraw) ? idxraw[2 * t] : idxraw[t];
  if (tid == 0) tok[t] = (l >= 0 && l < NLORA) ? l : -1;
  if (l < 0 || l >= NLORA) {
    if (tid < RANK) axo[t * RANK + tid] = 0.f;
    return;
  }
  float s0 = 0.f, s1 = 0.f, s2 = 0.f, s3 = 0.f;
  if (isb) {
    const unsigned short* xr = (const unsigned short*)xv + (size_t)t * HID;
    const unsigned short* Ab = (const unsigned short*)lav + ((size_t)l * RANK + wave * 4) * HID;
    #pragma unroll 4
    for (int i = 0; i < HID / 256; ++i) {
      const int h = (i * 64 + lane) * 4;
      const ushort4 u = *(const ushort4*)(xr + h);
      const float x0 = b2f(u.x), x1 = b2f(u.y), x2 = b2f(u.z), x3 = b2f(u.w);
      const ushort4 a0 = *(const ushort4*)(Ab + 0 * HID + h);
      const ushort4 a1 = *(const ushort4*)(Ab + 1 * HID + h);
      const ushort4 a2 = *(const ushort4*)(Ab + 2 * HID + h);
      const ushort4 a3 = *(const ushort4*)(Ab + 3 * HID + h);
      s0 += b2f(a0.x) * x0 + b2f(a0.y) * x1 + b2f(a0.z) * x2 + b2f(a0.w) * x3;
      s1 += b2f(a1.x) * x0 + b2f(a1.y) * x1 + b2f(a1.z) * x2 + b2f(a1.w) * x3;
      s2 += b2f(a2.x) * x0 + b2f(a2.y) * x1 + b2f(a2.z) * x2 + b2f(a2.w) * x3;
      s3 += b2f(a3.x) * x0 + b2f(a3.y) * x1 + b2f(a3.z) * x2 + b2f(a3.w) * x3;
    }
  } else {
    const float* xr = (const float*)xv + (size_t)t * HID;
    const float* Ab = (const float*)lav + ((size_t)l * RANK + wave * 4) * HID;
    #pragma unroll 4
    for (int i = 0; i < HID / 256; ++i) {
      const int h = (i * 64 + lane) * 4;
      const float4 x4 = *(const float4*)(xr + h);
      const float4 a0 = *(const float4*)(Ab + 0 * HID + h);
      const float4 a1 = *(const float4*)(Ab + 1 * HID + h);
      const float4 a2 = *(const float4*)(Ab + 2 * HID + h);
      const float4 a3 = *(const float4*)(Ab + 3 * HID + h);
      s0 += a0.x * x4.x + a0.y * x4.y + a0.z * x4.z + a0.w * x4.w;
      s1 += a1.x * x4.x + a1.y * x4.y + a1.z * x4.z + a1.w * x4.w;
      s2 += a2.x * x4.x + a2.y * x4.y + a2.z * x4.z + a2.w * x4.w;
      s3 += a3.x * x4.x + a3.y * x4.y + a3.z * x4.z + a3.w * x4.w;
    }
  }
  #pragma unroll
  for (int off = 32; off; off >>= 1) {
    s0 += __shfl_xor(s0, off, 64);
    s1 += __shfl_xor(s1, off, 64);
    s2 += __shfl_xor(s2, off, 64);
    s3 += __shfl_xor(s3, off, 64);
  }
  if (lane == 0) {
    axo[t * RANK + wave * 4 + 0] = s0;
    axo[t * RANK + wave * 4 + 1] = s1;
    axo[t * RANK + wave * 4 + 2] = s2;
    axo[t * RANK + wave * 4 + 3] = s3;
  }
}

// load 16 consecutive floats (fp32 or bf16 storage) into dst[16]
__device__ __forceinline__ void load16(const void* base, int isb, size_t elem_off,
                                       float* dst) {
  if (isb) {
    const ushort4* p = (const ushort4*)((const unsigned short*)base + elem_off);
    #pragma unroll
    for (int g = 0; g < 4; ++g) {
      const ushort4 q = p[g];
      dst[4 * g + 0] = b2f(q.x); dst[4 * g + 1] = b2f(q.y);
      dst[4 * g + 2] = b2f(q.z); dst[4 * g + 3] = b2f(q.w);
    }
  } else {
    const float4* p = (const float4*)((const float*)base + elem_off);
    #pragma unroll
    for (int g = 0; g < 4; ++g) {
      const float4 q = p[g];
      dst[4 * g + 0] = q.x; dst[4 * g + 1] = q.y;
      dst[4 * g + 2] = q.z; dst[4 * g + 3] = q.w;
    }
  }
}

// ---------------- main GEMM (+ fused bias & LoRA-B epilogue) --------------
// 128x128 tile, BK=64, double-buffered LDS (2 x 32KB), ONE barrier per
// interval: prefetch interval k+1 into the idle buffer, compute k.
// 8 waves, each 32x64 (2x4 frags, 16 MFMA per interval).
// LDS granule swizzle: row r, 16B-granule q in [0,8) stored at r*8+(q^(r&7))
// -> reads hit 2 lanes/bank (free); staging stays 128B-contiguous per row.
__global__ __launch_bounds__(512, 4) void gemm_kernel(
    const void* __restrict__ x_raw, const void* __restrict__ w_raw,
    const unsigned short* __restrict__ xb_ws, const unsigned short* __restrict__ wb_ws,
    const void* __restrict__ bias_raw, const void* __restrict__ lorab_raw,
    const float* __restrict__ axv, const int* __restrict__ tok,
    void* __restrict__ outv) {
  __shared__ char smem[65536];   // buf b at b*32768: A 16KB, B 16KB
  const int isb = detect_bf16(x_raw);
  const unsigned short* Xb = isb ? (const unsigned short*)x_raw : xb_ws;
  const unsigned short* Wb = isb ? (const unsigned short*)w_raw : wb_ws;

  const int tid = threadIdx.x;
  const int wave = tid >> 6;
  const int lane = tid & 63;
  const int t0 = blockIdx.y * 128;
  const int o0 = blockIdx.x * 128;
  const int wr = (wave >> 1) * 32;      // 4 row-groups of 32
  const int wc = (wave & 1) * 64;       // 2 col-groups of 64

  // staging source: wave w, issue p in {0,1}: granule s = w*128+p*64+lane,
  // row = s>>3, stored-q = s&7, tile-q = (s&7)^(row&7) = (lane&7)^(lane>>3)
  const int q_ = ((lane & 7) ^ (lane >> 3)) * 16;
  const size_t rA = (size_t)(t0 + wave * 16 + (lane >> 3));
  const size_t rB = (size_t)(o0 + wave * 16 + (lane >> 3));
  const char* gA0 = (const char*)Xb + (rA + 0) * (HID * 2) + q_;
  const char* gA1 = (const char*)Xb + (rA + 8) * (HID * 2) + q_;
  const char* gB0 = (const char*)Wb + (rB + 0) * (HID * 2) + q_;
  const char* gB1 = (const char*)Wb + (rB + 8) * (HID * 2) + q_;

  const int fm = lane & 15;
  const int fq = lane >> 4;
  const int sw = fm & 7;
  int aOff[2][2], bOff[4][2];
  #pragma unroll
  for (int i = 0; i < 2; ++i)
    #pragma unroll
    for (int kk = 0; kk < 2; ++kk)
      aOff[i][kk] = (wr + i * 16 + fm) * 128 + (((kk * 4 + fq) ^ sw) << 4);
  #pragma unroll
  for (int j = 0; j < 4; ++j)
    #pragma unroll
    for (int kk = 0; kk < 2; ++kk)
      bOff[j][kk] = 16384 + (wc + j * 16 + fm) * 128 + (((kk * 4 + fq) ^ sw) << 4);

  floatx4 acc[2][4];
  #pragma unroll
  for (int i = 0; i < 2; ++i)
    #pragma unroll
    for (int j = 0; j < 4; ++j)
      acc[i][j] = (floatx4){0.f, 0.f, 0.f, 0.f};

#define STAGE(K, B) do {                                        \
    const int kb_ = (K) * 128;                                  \
    char* d_ = smem + (B) * 32768 + wave * 2048;                \
    gld16(gA0 + kb_, d_);                                       \
    gld16(gA1 + kb_, d_ + 1024);                                \
    gld16(gB0 + kb_, d_ + 16384);                               \
    gld16(gB1 + kb_, d_ + 16384 + 1024);                        \
  } while (0)

#define COMPUTE(B) do {                                                     \
    const char* base_ = smem + (B) * 32768;                                 \
    _Pragma("unroll")                                                       \
    for (int kk = 0; kk < 2; ++kk) {                                        \
      bf16x8 a0 = *(const bf16x8*)(base_ + aOff[0][kk]);                    \
      bf16x8 a1 = *(const bf16x8*)(base_ + aOff[1][kk]);                    \
      bf16x8 b0 = *(const bf16x8*)(base_ + bOff[0][kk]);                    \
      bf16x8 b1 = *(const bf16x8*)(base_ + bOff[1][kk]);                    \
      bf16x8 b2 = *(const bf16x8*)(base_ + bOff[2][kk]);                    \
      bf16x8 b3 = *(const bf16x8*)(base_ + bOff[3][kk]);                    \
      acc[0][0] = __builtin_amdgcn_mfma_f32_16x16x32_bf16(a0, b0, acc[0][0], 0, 0, 0); \
      acc[0][1] = __builtin_amdgcn_mfma_f32_16x16x32_bf16(a0, b1, acc[0][1], 0, 0, 0); \
      acc[0][2] = __builtin_amdgcn_mfma_f32_16x16x32_bf16(a0, b2, acc[0][2], 0, 0, 0); \
      acc[0][3] = __builtin_amdgcn_mfma_f32_16x16x32_bf16(a0, b3, acc[0][3], 0, 0, 0); \
      acc[1][0] = __builtin_amdgcn_mfma_f32_16x16x32_bf16(a1, b0, acc[1][0], 0, 0, 0); \
      acc[1][1] = __builtin_amdgcn_mfma_f32_16x16x32_bf16(a1, b1, acc[1][1], 0, 0, 0); \
      acc[1][2] = __builtin_amdgcn_mfma_f32_16x16x32_bf16(a1, b2, acc[1][2], 0, 0, 0); \
      acc[1][3] = __builtin_amdgcn_mfma_f32_16x16x32_bf16(a1, b3, acc[1][3], 0, 0, 0); \
    }                                                                       \
  } while (0)

  const int KITER = HID * 2 / 128;   // 64
  STAGE(0, 0);
  for (int k = 0; k < KITER; k += 2) {
    __syncthreads();                  // waits vmcnt(0): STAGE(k) complete
    if (k + 1 < KITER) STAGE(k + 1, 1);
    COMPUTE(0);
    __syncthreads();                  // waits STAGE(k+1)
    if (k + 2 < KITER) STAGE(k + 2, 0);
    COMPUTE(1);
  }
#undef STAGE
#undef COMPUTE

  // epilogue: C/D layout col=lane&15, row=(lane>>4)*4+reg
  const int c = lane & 15;
  const int rr = (lane >> 4) * 4;
  float bv[4];
  #pragma unroll
  for (int j = 0; j < 4; ++j) {
    const int o = o0 + wc + j * 16 + c;
    bv[j] = isb ? b2f(((const unsigned short*)bias_raw)[o]) : ((const float*)bias_raw)[o];
  }
  unsigned short* outb = (unsigned short*)outv;
  float* outf = (float*)outv;
  #pragma unroll
  for (int mi = 0; mi < 2; ++mi) {
    #pragma unroll
    for (int r = 0; r < 4; ++r) {
      const int t = t0 + wr + mi * 16 + rr + r;
      const int l = tok[t];
      float axr[16];
      if (l >= 0) {
        const float4* ap = (const float4*)(axv + t * RANK);
        #pragma unroll
        for (int g = 0; g < 4; ++g) {
          const float4 q = ap[g];
          axr[4 * g] = q.x; axr[4 * g + 1] = q.y; axr[4 * g + 2] = q.z; axr[4 * g + 3] = q.w;
        }
      }
      #pragma unroll
      for (int j = 0; j < 4; ++j) {
        const int o = o0 + wc + j * 16 + c;
        float v = acc[mi][j][r] + bv[j];
        if (l >= 0) {
          float brow[16];
          load16(lorab_raw, isb, ((size_t)l * NOUT + o) * RANK, brow);
          float d = 0.f;
          #pragma unroll
          for (int g = 0; g < 16; ++g) d += brow[g] * axr[g];
          v += d;
        }
        const size_t oi = (size_t)t * NOUT + o;
        if (isb) outb[oi] = f2b(v); else outf[oi] = v;
      }
    }
  }
}

extern "C" void kernel_launch(void* const* d_in, const int* in_sizes, int n_in,
                              void* d_out, int out_size, void* d_ws, size_t ws_size,
                              hipStream_t stream) {
  const void* x  = d_in[0];
  const void* w  = d_in[1];
  const void* bs = d_in[2];
  const void* la = d_in[3];
  const void* lb = d_in[4];
  const int*  ix = (const int*)d_in[5];

  const size_t xb_bytes  = (size_t)NTOK * HID * 2;
  const size_t wb_bytes  = (size_t)NOUT * HID * 2;
  const size_t ax_bytes  = (size_t)NTOK * RANK * 4;
  const size_t tok_bytes = (size_t)NTOK * 4;
  const size_t full_need = xb_bytes + wb_bytes + ax_bytes + tok_bytes + 64;

  char* ws = (char*)d_ws;
  unsigned short *xb, *wb2;
  float* axp; int* tok;
  const bool full = ws_size >= full_need;
  if (full) {
    xb    = (unsigned short*)ws;
    wb2   = (unsigned short*)(ws + xb_bytes);
    axp   = (float*)(ws + xb_bytes + wb_bytes);
    tok   = (int*)(ws + xb_bytes + wb_bytes + ax_bytes);
  } else {
    axp   = (float*)ws;
    tok   = (int*)(ws + ax_bytes);
    xb    = (unsigned short*)x;   // small-ws fallback: assume raw already bf16
    wb2   = (unsigned short*)w;
  }

  prep_kernel<<<NTOK + 512, 256, 0, stream>>>(
      x, w, la, ix, xb, wb2, axp, tok, full ? 1 : 0);
  gemm_kernel<<<dim3(NOUT / 128, NTOK / 128), 512, 0, stream>>>(
      x, w, xb, wb2, bs, lb, axp, tok, d_out);
}

// Round 4
// 268.299 us; speedup vs baseline: 1.1073x; 1.0114x over previous
//
#include <hip/hip_runtime.h>

#define NTOK 2048
#define HID 4096
#define NOUT 4096
#define NLORA 16
#define RANK 16

typedef float floatx4 __attribute__((ext_vector_type(4)));
typedef __bf16 bf16x8 __attribute__((ext_vector_type(8)));

__device__ __forceinline__ unsigned short f2b(float f) {
  unsigned int u = __float_as_uint(f);
  u += 0x7FFFu + ((u >> 16) & 1u);   // round-to-nearest-even
  return (unsigned short)(u >> 16);
}
__device__ __forceinline__ float b2f(unsigned short u) {
  return __uint_as_float(((unsigned int)u) << 16);
}

// async global->LDS, 16 bytes per lane; LDS dest is wave-uniform base + lane*16
__device__ __forceinline__ void gld16(const char* g, char* l) {
  __builtin_amdgcn_global_load_lds(
      (const __attribute__((address_space(1))) unsigned int*)g,
      (__attribute__((address_space(3))) unsigned int*)l,
      16, 0, 0);
}

// ---- inline per-wave dtype detection ----
__device__ __forceinline__ int detect_bf16(const void* xraw) {
  const int lane = threadIdx.x & 63;
  const int e = (((const unsigned short*)xraw)[2 * lane] >> 7) & 0xFF;
  const unsigned long long wild = __ballot(e < 96 || e > 159);
  return wild == 0ull;
}
__device__ __forceinline__ int detect_i64(const int* idxraw) {
  const int lane = threadIdx.x & 63;
  const unsigned long long nz = __ballot((lane & 1) && idxraw[lane] != 0);
  return nz == 0ull;
}

// -------- prep: zero ax_all, write tok, convert X/W/A fp32->bf16 ----------
__global__ __launch_bounds__(256) void prep_kernel(
    const void* __restrict__ xv, const void* __restrict__ wv,
    const void* __restrict__ lav, const int* __restrict__ idxraw,
    unsigned short* __restrict__ xb, unsigned short* __restrict__ wb,
    unsigned short* __restrict__ ab, float* __restrict__ axall,
    int* __restrict__ tok, int do_conv) {
  const int gid = blockIdx.x * 256 + threadIdx.x;   // grid 2048*256 = 524288
  // zero ax_all (NTOK*256 floats = 131072 float4)
  if (gid < NTOK * 256 / 4) ((float4*)axall)[gid] = make_float4(0.f, 0.f, 0.f, 0.f);
  // tok
  const int i64 = detect_i64(idxraw);
  if (gid < NTOK) {
    const int l = i64 ? idxraw[2 * gid] : idxraw[gid];
    tok[gid] = (l >= 0 && l < NLORA) ? l : -1;
  }
  if (detect_bf16(xv) || !do_conv) return;   // already bf16: nothing to convert
  const int X8 = NTOK * HID / 8;
  const int W8 = NOUT * HID / 8;
  const int A8 = NLORA * RANK * HID / 8;
  const int TOT = X8 + W8 + A8;
  for (int i = gid; i < TOT; i += NTOK * 256) {
    const float* s; unsigned short* d; int j;
    if (i < X8) { s = (const float*)xv; d = xb; j = i; }
    else if (i < X8 + W8) { s = (const float*)wv; d = wb; j = i - X8; }
    else { s = (const float*)lav; d = ab; j = i - X8 - W8; }
    const float4 a = ((const float4*)s)[2 * j];
    const float4 b = ((const float4*)s)[2 * j + 1];
    union { unsigned short us[8]; uint4 v; } p;
    p.us[0] = f2b(a.x); p.us[1] = f2b(a.y); p.us[2] = f2b(a.z); p.us[3] = f2b(a.w);
    p.us[4] = f2b(b.x); p.us[5] = f2b(b.y); p.us[6] = f2b(b.z); p.us[7] = f2b(b.w);
    ((uint4*)d)[j] = p.v;
  }
}

// -------- axall: ax_all[t][n] += X(t,:) . Acat(n,:) over K-slice ----------
// M=2048, N=256 (n = l*16+r), K=4096 split 8 ways; 128x256 tile, 8 waves,
// each wave 64x64 (4x4 frags), single-buffer 2-barrier, fp32 atomicAdd out.
__global__ __launch_bounds__(512) void axall_kernel(
    const void* __restrict__ x_raw, const void* __restrict__ la_raw,
    const unsigned short* __restrict__ xb_ws, const unsigned short* __restrict__ ab_ws,
    float* __restrict__ axall) {
  __shared__ char smem[49152];   // X-tile 16KB @0, Acat-tile 32KB @16384
  const int isb = detect_bf16(x_raw);
  const unsigned short* Xb = isb ? (const unsigned short*)x_raw : xb_ws;
  const unsigned short* Ab = isb ? (const unsigned short*)la_raw : ab_ws;

  const int tid = threadIdx.x;
  const int wave = tid >> 6;
  const int lane = tid & 63;
  const int t0 = blockIdx.x * 128;
  const size_t ksb = (size_t)blockIdx.y * 512 * 2;   // K-slice byte offset
  const int wr = (wave >> 2) * 64;   // 2 row groups of 64
  const int wc = (wave & 3) * 64;    // 4 col groups of 64

  const int q_ = ((lane & 7) ^ (lane >> 3)) * 16;
  const char* gA = (const char*)Xb + (size_t)(t0 + wave * 16 + (lane >> 3)) * (HID * 2) + ksb + q_;
  const char* gB = (const char*)Ab + (size_t)(wave * 32 + (lane >> 3)) * (HID * 2) + ksb + q_;

  const int fm = lane & 15;
  const int fq = lane >> 4;
  const int sw = fm & 7;
  int aOff[4][2], bOff[4][2];
  #pragma unroll
  for (int i = 0; i < 4; ++i)
    #pragma unroll
    for (int kk = 0; kk < 2; ++kk) {
      aOff[i][kk] = (wr + i * 16 + fm) * 128 + (((kk * 4 + fq) ^ sw) << 4);
      bOff[i][kk] = 16384 + (wc + i * 16 + fm) * 128 + (((kk * 4 + fq) ^ sw) << 4);
    }

  floatx4 acc[4][4];
  #pragma unroll
  for (int i = 0; i < 4; ++i)
    #pragma unroll
    for (int j = 0; j < 4; ++j)
      acc[i][j] = (floatx4){0.f, 0.f, 0.f, 0.f};

  for (int it = 0; it < 8; ++it) {     // 8 intervals x BK=64 = 512 K-slice
    const int kb = it * 128;
    char* dA = smem + wave * 2048;
    char* dB = smem + 16384 + wave * 4096;
    gld16(gA + kb, dA);
    gld16(gA + (size_t)8 * (HID * 2) + kb, dA + 1024);
    gld16(gB + kb, dB);
    gld16(gB + (size_t)8 * (HID * 2) + kb, dB + 1024);
    gld16(gB + (size_t)16 * (HID * 2) + kb, dB + 2048);
    gld16(gB + (size_t)24 * (HID * 2) + kb, dB + 3072);
    __syncthreads();
    #pragma unroll
    for (int kk = 0; kk < 2; ++kk) {
      bf16x8 af[4], bf[4];
      #pragma unroll
      for (int i = 0; i < 4; ++i) af[i] = *(const bf16x8*)(smem + aOff[i][kk]);
      #pragma unroll
      for (int j = 0; j < 4; ++j) bf[j] = *(const bf16x8*)(smem + bOff[j][kk]);
      #pragma unroll
      for (int i = 0; i < 4; ++i)
        #pragma unroll
        for (int j = 0; j < 4; ++j)
          acc[i][j] = __builtin_amdgcn_mfma_f32_16x16x32_bf16(af[i], bf[j], acc[i][j], 0, 0, 0);
    }
    __syncthreads();
  }

  const int c = lane & 15;
  const int rr = (lane >> 4) * 4;
  #pragma unroll
  for (int i = 0; i < 4; ++i)
    #pragma unroll
    for (int r = 0; r < 4; ++r) {
      const int t = t0 + wr + i * 16 + rr + r;
      #pragma unroll
      for (int j = 0; j < 4; ++j) {
        const int n = wc + j * 16 + c;
        atomicAdd(&axall[(size_t)t * 256 + n], acc[i][j][r]);
      }
    }
}

// load 16 consecutive floats (fp32 or bf16 storage) into dst[16]
__device__ __forceinline__ void load16(const void* base, int isb, size_t elem_off,
                                       float* dst) {
  if (isb) {
    const ushort4* p = (const ushort4*)((const unsigned short*)base + elem_off);
    #pragma unroll
    for (int g = 0; g < 4; ++g) {
      const ushort4 q = p[g];
      dst[4 * g + 0] = b2f(q.x); dst[4 * g + 1] = b2f(q.y);
      dst[4 * g + 2] = b2f(q.z); dst[4 * g + 3] = b2f(q.w);
    }
  } else {
    const float4* p = (const float4*)((const float*)base + elem_off);
    #pragma unroll
    for (int g = 0; g < 4; ++g) {
      const float4 q = p[g];
      dst[4 * g + 0] = q.x; dst[4 * g + 1] = q.y;
      dst[4 * g + 2] = q.z; dst[4 * g + 3] = q.w;
    }
  }
}

// ---------------- main GEMM (+ fused bias & LoRA-B epilogue) --------------
// 128x128 tile, BK=64, double-buffered LDS, one barrier per interval.
// 1-D grid 512, XCD-compact decode: xcd = id&7 owns an 8x8 (t-tile x o-tile)
// sub-grid so its per-interval working set (16 x 8KB slices) stays in its
// 4MB L2 -> staging served from L2 (34.5 TB/s agg) instead of LLC (~10.5).
__global__ __launch_bounds__(512, 4) void gemm_kernel(
    const void* __restrict__ x_raw, const void* __restrict__ w_raw,
    const unsigned short* __restrict__ xb_ws, const unsigned short* __restrict__ wb_ws,
    const void* __restrict__ bias_raw, const void* __restrict__ lorab_raw,
    const float* __restrict__ axv, const int* __restrict__ tok,
    void* __restrict__ outv) {
  __shared__ char smem[65536];   // buf b at b*32768: A 16KB, B 16KB
  const int isb = detect_bf16(x_raw);
  const unsigned short* Xb = isb ? (const unsigned short*)x_raw : xb_ws;
  const unsigned short* Wb = isb ? (const unsigned short*)w_raw : wb_ws;

  const int tid = threadIdx.x;
  const int wave = tid >> 6;
  const int lane = tid & 63;
  // XCD-compact swizzle (bijective on 16x32 tile grid)
  const int id = blockIdx.x;
  const int xcd = id & 7;
  const int slot = id >> 3;                 // 0..63
  const int bt = (xcd & 1) * 8 + (slot >> 3);
  const int bo = (xcd >> 1) * 8 + (slot & 7);
  const int t0 = bt * 128;
  const int o0 = bo * 128;
  const int wr = (wave >> 1) * 32;      // 4 row-groups of 32
  const int wc = (wave & 1) * 64;       // 2 col-groups of 64

  const int q_ = ((lane & 7) ^ (lane >> 3)) * 16;
  const size_t rA = (size_t)(t0 + wave * 16 + (lane >> 3));
  const size_t rB = (size_t)(o0 + wave * 16 + (lane >> 3));
  const char* gA0 = (const char*)Xb + (rA + 0) * (HID * 2) + q_;
  const char* gA1 = (const char*)Xb + (rA + 8) * (HID * 2) + q_;
  const char* gB0 = (const char*)Wb + (rB + 0) * (HID * 2) + q_;
  const char* gB1 = (const char*)Wb + (rB + 8) * (HID * 2) + q_;

  const int fm = lane & 15;
  const int fq = lane >> 4;
  const int sw = fm & 7;
  int aOff[2][2], bOff[4][2];
  #pragma unroll
  for (int i = 0; i < 2; ++i)
    #pragma unroll
    for (int kk = 0; kk < 2; ++kk)
      aOff[i][kk] = (wr + i * 16 + fm) * 128 + (((kk * 4 + fq) ^ sw) << 4);
  #pragma unroll
  for (int j = 0; j < 4; ++j)
    #pragma unroll
    for (int kk = 0; kk < 2; ++kk)
      bOff[j][kk] = 16384 + (wc + j * 16 + fm) * 128 + (((kk * 4 + fq) ^ sw) << 4);

  floatx4 acc[2][4];
  #pragma unroll
  for (int i = 0; i < 2; ++i)
    #pragma unroll
    for (int j = 0; j < 4; ++j)
      acc[i][j] = (floatx4){0.f, 0.f, 0.f, 0.f};

#define STAGE(K, B) do {                                        \
    const int kb_ = (K) * 128;                                  \
    char* d_ = smem + (B) * 32768 + wave * 2048;                \
    gld16(gA0 + kb_, d_);                                       \
    gld16(gA1 + kb_, d_ + 1024);                                \
    gld16(gB0 + kb_, d_ + 16384);                               \
    gld16(gB1 + kb_, d_ + 16384 + 1024);                        \
  } while (0)

#define COMPUTE(B) do {                                                     \
    const char* base_ = smem + (B) * 32768;                                 \
    _Pragma("unroll")                                                       \
    for (int kk = 0; kk < 2; ++kk) {                                        \
      bf16x8 a0 = *(const bf16x8*)(base_ + aOff[0][kk]);                    \
      bf16x8 a1 = *(const bf16x8*)(base_ + aOff[1][kk]);                    \
      bf16x8 b0 = *(const bf16x8*)(base_ + bOff[0][kk]);                    \
      bf16x8 b1 = *(const bf16x8*)(base_ + bOff[1][kk]);                    \
      bf16x8 b2 = *(const bf16x8*)(base_ + bOff[2][kk]);                    \
      bf16x8 b3 = *(const bf16x8*)(base_ + bOff[3][kk]);                    \
      acc[0][0] = __builtin_amdgcn_mfma_f32_16x16x32_bf16(a0, b0, acc[0][0], 0, 0, 0); \
      acc[0][1] = __builtin_amdgcn_mfma_f32_16x16x32_bf16(a0, b1, acc[0][1], 0, 0, 0); \
      acc[0][2] = __builtin_amdgcn_mfma_f32_16x16x32_bf16(a0, b2, acc[0][2], 0, 0, 0); \
      acc[0][3] = __builtin_amdgcn_mfma_f32_16x16x32_bf16(a0, b3, acc[0][3], 0, 0, 0); \
      acc[1][0] = __builtin_amdgcn_mfma_f32_16x16x32_bf16(a1, b0, acc[1][0], 0, 0, 0); \
      acc[1][1] = __builtin_amdgcn_mfma_f32_16x16x32_bf16(a1, b1, acc[1][1], 0, 0, 0); \
      acc[1][2] = __builtin_amdgcn_mfma_f32_16x16x32_bf16(a1, b2, acc[1][2], 0, 0, 0); \
      acc[1][3] = __builtin_amdgcn_mfma_f32_16x16x32_bf16(a1, b3, acc[1][3], 0, 0, 0); \
    }                                                                       \
  } while (0)

  const int KITER = HID * 2 / 128;   // 64
  STAGE(0, 0);
  for (int k = 0; k < KITER; k += 2) {
    __syncthreads();                  // waits vmcnt(0): STAGE(k) complete
    if (k + 1 < KITER) STAGE(k + 1, 1);
    COMPUTE(0);
    __syncthreads();                  // waits STAGE(k+1)
    if (k + 2 < KITER) STAGE(k + 2, 0);
    COMPUTE(1);
  }
#undef STAGE
#undef COMPUTE

  // epilogue: C/D layout col=lane&15, row=(lane>>4)*4+reg
  const int c = lane & 15;
  const int rr = (lane >> 4) * 4;
  float bv[4];
  #pragma unroll
  for (int j = 0; j < 4; ++j) {
    const int o = o0 + wc + j * 16 + c;
    bv[j] = isb ? b2f(((const unsigned short*)bias_raw)[o]) : ((const float*)bias_raw)[o];
  }
  unsigned short* outb = (unsigned short*)outv;
  float* outf = (float*)outv;
  #pragma unroll
  for (int mi = 0; mi < 2; ++mi) {
    #pragma unroll
    for (int r = 0; r < 4; ++r) {
      const int t = t0 + wr + mi * 16 + rr + r;
      const int l = tok[t];
      float axr[16];
      if (l >= 0) {
        const float4* ap = (const float4*)(axv + (size_t)t * 256 + l * 16);
        #pragma unroll
        for (int g = 0; g < 4; ++g) {
          const float4 q = ap[g];
          axr[4 * g] = q.x; axr[4 * g + 1] = q.y; axr[4 * g + 2] = q.z; axr[4 * g + 3] = q.w;
        }
      }
      #pragma unroll
      for (int j = 0; j < 4; ++j) {
        const int o = o0 + wc + j * 16 + c;
        float v = acc[mi][j][r] + bv[j];
        if (l >= 0) {
          float brow[16];
          load16(lorab_raw, isb, ((size_t)l * NOUT + o) * RANK, brow);
          float d = 0.f;
          #pragma unroll
          for (int g = 0; g < 16; ++g) d += brow[g] * axr[g];
          v += d;
        }
        const size_t oi = (size_t)t * NOUT + o;
        if (isb) outb[oi] = f2b(v); else outf[oi] = v;
      }
    }
  }
}

extern "C" void kernel_launch(void* const* d_in, const int* in_sizes, int n_in,
                              void* d_out, int out_size, void* d_ws, size_t ws_size,
                              hipStream_t stream) {
  const void* x  = d_in[0];
  const void* w  = d_in[1];
  const void* bs = d_in[2];
  const void* la = d_in[3];
  const void* lb = d_in[4];
  const int*  ix = (const int*)d_in[5];

  const size_t xb_bytes  = (size_t)NTOK * HID * 2;
  const size_t wb_bytes  = (size_t)NOUT * HID * 2;
  const size_t ab_bytes  = (size_t)NLORA * RANK * HID * 2;
  const size_t ax_bytes  = (size_t)NTOK * 256 * 4;
  const size_t tok_bytes = (size_t)NTOK * 4;
  const size_t full_need = xb_bytes + wb_bytes + ab_bytes + ax_bytes + tok_bytes + 64;

  char* ws = (char*)d_ws;
  unsigned short *xb, *wb2, *ab;
  float* axp; int* tok;
  const bool full = ws_size >= full_need;
  if (full) {
    xb    = (unsigned short*)ws;
    wb2   = (unsigned short*)(ws + xb_bytes);
    ab    = (unsigned short*)(ws + xb_bytes + wb_bytes);
    axp   = (float*)(ws + xb_bytes + wb_bytes + ab_bytes);
    tok   = (int*)(ws + xb_bytes + wb_bytes + ab_bytes + ax_bytes);
  } else {
    axp   = (float*)ws;
    tok   = (int*)(ws + ax_bytes);
    xb    = (unsigned short*)x;   // small-ws fallback: assume raw already bf16
    wb2   = (unsigned short*)w;
    ab    = (unsigned short*)la;
  }

  prep_kernel<<<NTOK, 256, 0, stream>>>(x, w, la, ix, xb, wb2, ab, axp, tok,
                                        full ? 1 : 0);
  axall_kernel<<<dim3(NTOK / 128, 8), 512, 0, stream>>>(x, la, xb, ab, axp);
  gemm_kernel<<<512, 512, 0, stream>>>(x, w, xb, wb2, bs, lb, axp, tok, d_out);
}

// Round 5
// 267.350 us; speedup vs baseline: 1.1112x; 1.0036x over previous
//
#include <hip/hip_runtime.h>

#define NTOK 2048
#define HID 4096
#define NOUT 4096
#define NLORA 16
#define RANK 16

typedef float floatx4 __attribute__((ext_vector_type(4)));
typedef __bf16 bf16x8 __attribute__((ext_vector_type(8)));

__device__ __forceinline__ unsigned short f2b(float f) {
  unsigned int u = __float_as_uint(f);
  u += 0x7FFFu + ((u >> 16) & 1u);   // round-to-nearest-even
  return (unsigned short)(u >> 16);
}
__device__ __forceinline__ float b2f(unsigned short u) {
  return __uint_as_float(((unsigned int)u) << 16);
}
__device__ __forceinline__ unsigned int pk2(float a, float b) {
  return (unsigned int)f2b(a) | ((unsigned int)f2b(b) << 16);
}

// async global->LDS, 16 B/lane; LDS dest is wave-uniform base (+ lane*16 in HW)
__device__ __forceinline__ void gld16(const char* g, char* l) {
  __builtin_amdgcn_global_load_lds(
      (const __attribute__((address_space(1))) unsigned int*)g,
      (__attribute__((address_space(3))) unsigned int*)l,
      16, 0, 0);
}

// ---- inline per-wave dtype detection ----
__device__ __forceinline__ int detect_bf16(const void* xraw) {
  const int lane = threadIdx.x & 63;
  const int e = (((const unsigned short*)xraw)[2 * lane] >> 7) & 0xFF;
  const unsigned long long wild = __ballot(e < 96 || e > 159);
  return wild == 0ull;
}
__device__ __forceinline__ int detect_i64(const int* idxraw) {
  const int lane = threadIdx.x & 63;
  const unsigned long long nz = __ballot((lane & 1) && idxraw[lane] != 0);
  return nz == 0ull;
}

// ============ prep: axall slices (+X conversion side-effect) + W conversion ==
// blocks [0, 32*nks): axall: axpart[ks][t][n] = X(t, kslice) . Acat(n, kslice)
//   tile 128t x 128n, 4 waves of 64x64, BK=32, VGPR-staged fp32->bf16 (or bf16
//   direct). nt==0 blocks also write the converted X tile to xb.
// blocks [32*nks, +2048): W fp32->bf16 grid-stride conversion.
__global__ __launch_bounds__(256) void prep_kernel(
    const void* __restrict__ xv, const void* __restrict__ wv,
    const void* __restrict__ lav,
    unsigned short* __restrict__ xb, unsigned short* __restrict__ wb,
    float* __restrict__ axpart, int nks, int full) {
  const int tid = threadIdx.x;
  const int isb = detect_bf16(xv);
  const int AXB = 32 * nks;
  if (blockIdx.x >= AXB) {
    if (isb || !full) return;
    const int W8 = NOUT * HID / 8;
    const int cb = blockIdx.x - AXB;
    for (int i = cb * 256 + tid; i < W8; i += 2048 * 256) {
      const float4 a = ((const float4*)wv)[2 * i];
      const float4 b = ((const float4*)wv)[2 * i + 1];
      uint4 p;
      p.x = pk2(a.x, a.y); p.y = pk2(a.z, a.w);
      p.z = pk2(b.x, b.y); p.w = pk2(b.z, b.w);
      ((uint4*)wb)[i] = p;
    }
    return;
  }
  __shared__ char sm[16384];           // X 8KB @0, Acat 8KB @8192 (64B rows)
  const int b = blockIdx.x;
  const int tt = b & 15, nt = (b >> 4) & 1, ks = b >> 5;
  const int t0 = tt * 128, n0 = nt * 128;
  const int kslice = HID / nks;
  const int k0 = ks * kslice;
  const int wave = tid >> 6, lane = tid & 63;
  const int isx = tid < 128;
  const int row = isx ? tid : tid - 128;
  const size_t gbase = (size_t)((isx ? t0 : n0) + row) * HID + k0;
  const float* srcF = (isx ? (const float*)xv : (const float*)lav) + gbase;
  const unsigned short* srcB =
      (isx ? (const unsigned short*)xv : (const unsigned short*)lav) + gbase;
  char* ldsrow = sm + (isx ? 0 : 8192) + row * 64;
  const int prm = (tid >> 1) & 3;      // (row>>1)&3
  const int wrxb = (isx && nt == 0 && !isb && full);
  unsigned short* xbrow = xb + (size_t)(t0 + row) * HID + k0;

  const int wr = (wave >> 1) * 64, wc = (wave & 1) * 64;
  const int fm = lane & 15, fq = lane >> 4;
  const int sw2 = (fm >> 1) & 3;
  int aO[4], bO[4];
  #pragma unroll
  for (int i = 0; i < 4; ++i) {
    aO[i] = (wr + i * 16 + fm) * 64 + ((fq ^ sw2) << 4);
    bO[i] = 8192 + (wc + i * 16 + fm) * 64 + ((fq ^ sw2) << 4);
  }
  floatx4 acc[4][4];
  #pragma unroll
  for (int i = 0; i < 4; ++i)
    #pragma unroll
    for (int j = 0; j < 4; ++j) acc[i][j] = (floatx4){0.f, 0.f, 0.f, 0.f};

  const int NIT = kslice / 32;
  for (int it = 0; it < NIT; ++it) {
    uint4 w[4];
    if (isb) {
      const uint4* s4 = (const uint4*)(srcB + it * 32);
      #pragma unroll
      for (int g = 0; g < 4; ++g) w[g] = s4[g];
    } else {
      const float4* s4 = (const float4*)(srcF + it * 32);
      #pragma unroll
      for (int g = 0; g < 4; ++g) {
        const float4 f0 = s4[2 * g], f1 = s4[2 * g + 1];
        w[g].x = pk2(f0.x, f0.y); w[g].y = pk2(f0.z, f0.w);
        w[g].z = pk2(f1.x, f1.y); w[g].w = pk2(f1.z, f1.w);
      }
      if (wrxb) {
        uint4* d = (uint4*)(xbrow + it * 32);
        #pragma unroll
        for (int g = 0; g < 4; ++g) d[g] = w[g];
      }
    }
    #pragma unroll
    for (int g = 0; g < 4; ++g)
      *(uint4*)(ldsrow + ((g ^ prm) << 4)) = w[g];
    __syncthreads();
    bf16x8 af[4], bfv[4];
    #pragma unroll
    for (int i = 0; i < 4; ++i) af[i] = *(const bf16x8*)(sm + aO[i]);
    #pragma unroll
    for (int j = 0; j < 4; ++j) bfv[j] = *(const bf16x8*)(sm + bO[j]);
    #pragma unroll
    for (int i = 0; i < 4; ++i)
      #pragma unroll
      for (int j = 0; j < 4; ++j)
        acc[i][j] = __builtin_amdgcn_mfma_f32_16x16x32_bf16(af[i], bfv[j], acc[i][j], 0, 0, 0);
    __syncthreads();
  }
  const int c = lane & 15, rr = (lane >> 4) * 4;
  #pragma unroll
  for (int i = 0; i < 4; ++i)
    #pragma unroll
    for (int r = 0; r < 4; ++r) {
      const int t = t0 + wr + i * 16 + rr + r;
      float* dst = axpart + ((size_t)ks * NTOK + t) * 256 + n0 + wc;
      #pragma unroll
      for (int j = 0; j < 4; ++j) dst[j * 16 + c] = acc[i][j][r];
    }
}

// ============ main GEMM (+ fused bias & LoRA-B epilogue) =====================
// TM=256 x TN=128, 8 waves of 64x64 (4x4 frags, 16x16x32), BK=32 double-
// buffered (2 x 24KB), one barrier per interval, gld16 staging, swizzle
// q^((row>>1)&3) on 64B rows (conflict-free frag reads).
// Epilogue: ax/tok tables + bf16 lora_B (two 8-lora halves) cached in LDS.
__global__ __launch_bounds__(512, 2) void gemm_kernel(
    const void* __restrict__ x_raw, const void* __restrict__ w_raw,
    const unsigned short* __restrict__ xb_ws, const unsigned short* __restrict__ wb_ws,
    const void* __restrict__ bias_raw, const void* __restrict__ lorab_raw,
    const float* __restrict__ axpart, const int* __restrict__ idxraw,
    int nks, void* __restrict__ outv) {
  __shared__ char smem[50176];  // K-loop: buf b @ b*24576 (A 16K, B 8K)
                                // phase2: Bl 32K @0, axs 16K @32768, tok @49152
  const int isb = detect_bf16(x_raw);
  const int i64 = detect_i64(idxraw);
  const unsigned short* Xb = isb ? (const unsigned short*)x_raw : xb_ws;
  const unsigned short* Wb = isb ? (const unsigned short*)w_raw : wb_ws;

  const int tid = threadIdx.x;
  const int wave = tid >> 6;
  const int lane = tid & 63;
  // XCD-compact: xcd owns 4 o-tiles x 8 t-tiles
  const int id = blockIdx.x;
  const int xcd = id & 7, slot = id >> 3;
  const int o0 = (xcd * 4 + (slot & 3)) * 128;
  const int t0 = (slot >> 2) * 256;
  const int wr = (wave >> 1) * 64;     // 4 row-groups of 64
  const int wc = (wave & 1) * 64;      // 2 col-groups of 64

  // staging: granule s covers row s>>2, stored q = s&3 = tile_q ^ ((row>>1)&3)
  const int q_ = ((lane & 3) ^ ((lane >> 3) & 3)) * 16;
  const int srw = (lane >> 2);
  const char* gA0 = (const char*)Xb + (size_t)(t0 + 0 + wave * 16 + srw) * (HID * 2) + q_;
  const char* gA1 = (const char*)Xb + (size_t)(t0 + 128 + wave * 16 + srw) * (HID * 2) + q_;
  const char* gB0 = (const char*)Wb + (size_t)(o0 + wave * 16 + srw) * (HID * 2) + q_;

  const int fm = lane & 15, fq = lane >> 4;
  const int sw2 = (fm >> 1) & 3;
  int aOff[4], bOff[4];
  #pragma unroll
  for (int i = 0; i < 4; ++i) {
    aOff[i] = (wr + i * 16 + fm) * 64 + ((fq ^ sw2) << 4);
    bOff[i] = 16384 + (wc + i * 16 + fm) * 64 + ((fq ^ sw2) << 4);
  }
  floatx4 acc[4][4];
  #pragma unroll
  for (int i = 0; i < 4; ++i)
    #pragma unroll
    for (int j = 0; j < 4; ++j) acc[i][j] = (floatx4){0.f, 0.f, 0.f, 0.f};

#define STAGE(K, B) do {                                  \
    const size_t kb_ = (size_t)(K) * 64;                  \
    char* d_ = smem + (B) * 24576 + wave * 1024;          \
    gld16(gA0 + kb_, d_);                                 \
    gld16(gA1 + kb_, d_ + 8192);                          \
    gld16(gB0 + kb_, d_ + 16384);                         \
  } while (0)

#define COMPUTE(B) do {                                                         \
    const char* base_ = smem + (B) * 24576;                                     \
    bf16x8 af[4], bfv[4];                                                       \
    _Pragma("unroll")                                                           \
    for (int i = 0; i < 4; ++i) af[i] = *(const bf16x8*)(base_ + aOff[i]);      \
    _Pragma("unroll")                                                           \
    for (int j = 0; j < 4; ++j) bfv[j] = *(const bf16x8*)(base_ + bOff[j]);     \
    _Pragma("unroll")                                                           \
    for (int i = 0; i < 4; ++i)                                                 \
      _Pragma("unroll")                                                         \
      for (int j = 0; j < 4; ++j)                                               \
        acc[i][j] = __builtin_amdgcn_mfma_f32_16x16x32_bf16(af[i], bfv[j], acc[i][j], 0, 0, 0); \
  } while (0)

  const int KITER = HID / 32;   // 128
  STAGE(0, 0);
  for (int k = 0; k < KITER; k += 2) {
    __syncthreads();
    if (k + 1 < KITER) STAGE(k + 1, 1);
    COMPUTE(0);
    __syncthreads();
    if (k + 2 < KITER) STAGE(k + 2, 0);
    COMPUTE(1);
  }
#undef STAGE
#undef COMPUTE
  __syncthreads();

  // ---- phase 2a: build ax (slice-summed, l-window) + tok tables in LDS ----
  {
    const int t_l = tid >> 1, h8 = (tid & 1) * 8;
    const int t = t0 + t_l;
    int l = i64 ? idxraw[2 * t] : idxraw[t];
    if (l < 0 || l >= NLORA) l = -1;
    if ((tid & 1) == 0) *(int*)(smem + 49152 + t_l * 4) = l;
    float4 s0 = make_float4(0.f, 0.f, 0.f, 0.f), s1 = s0;
    if (l >= 0) {
      for (int s = 0; s < nks; ++s) {
        const float4* p = (const float4*)(axpart + ((size_t)s * NTOK + t) * 256 + l * 16 + h8);
        const float4 a = p[0], bq = p[1];
        s0.x += a.x; s0.y += a.y; s0.z += a.z; s0.w += a.w;
        s1.x += bq.x; s1.y += bq.y; s1.z += bq.z; s1.w += bq.w;
      }
    }
    float4* d = (float4*)(smem + 32768 + t_l * 64 + h8 * 4);
    d[0] = s0; d[1] = s1;
  }
  // bias (global, tiny)
  const int c = lane & 15;
  const int rr = (lane >> 4) * 4;
  float bv[4];
  #pragma unroll
  for (int j = 0; j < 4; ++j) {
    const int o = o0 + wc + j * 16 + c;
    bv[j] = isb ? b2f(((const unsigned short*)bias_raw)[o]) : ((const float*)bias_raw)[o];
  }
  // ---- phase 2b: two 8-lora halves of B cached in LDS as bf16 ----
  const int ol_ld = tid >> 2, rq = (tid & 3) * 4;
  #pragma unroll
  for (int h = 0; h < 2; ++h) {
    __syncthreads();
    #pragma unroll
    for (int lh = 0; lh < 8; ++lh) {
      const int l = h * 8 + lh;
      const size_t eoff = ((size_t)l * NOUT + o0 + ol_ld) * RANK + rq;
      uint2 pv;
      if (isb) {
        pv = *(const uint2*)((const unsigned short*)lorab_raw + eoff);
      } else {
        const float4 v = *(const float4*)((const float*)lorab_raw + eoff);
        pv.x = pk2(v.x, v.y); pv.y = pk2(v.z, v.w);
      }
      *(uint2*)(smem + lh * 4096 + ol_ld * 32 + rq * 2) = pv;
    }
    __syncthreads();
    #pragma unroll
    for (int mi = 0; mi < 4; ++mi) {
      #pragma unroll
      for (int r = 0; r < 4; ++r) {
        const int tl = wr + mi * 16 + rr + r;
        const int l = *(const int*)(smem + 49152 + tl * 4);
        if (l < 0 || (l >> 3) != h) continue;
        float axr[16];
        {
          const float4* ap = (const float4*)(smem + 32768 + tl * 64);
          #pragma unroll
          for (int g = 0; g < 4; ++g) {
            const float4 q = ap[g];
            axr[4 * g] = q.x; axr[4 * g + 1] = q.y;
            axr[4 * g + 2] = q.z; axr[4 * g + 3] = q.w;
          }
        }
        #pragma unroll
        for (int j = 0; j < 4; ++j) {
          const int ol = wc + j * 16 + c;
          const uint4 q0 = *(const uint4*)(smem + (l & 7) * 4096 + ol * 32);
          const uint4 q1 = *(const uint4*)(smem + (l & 7) * 4096 + ol * 32 + 16);
          float d = 0.f;
          const unsigned int qa[8] = {q0.x, q0.y, q0.z, q0.w, q1.x, q1.y, q1.z, q1.w};
          #pragma unroll
          for (int g = 0; g < 8; ++g) {
            d += b2f((unsigned short)(qa[g] & 0xFFFF)) * axr[2 * g];
            d += b2f((unsigned short)(qa[g] >> 16)) * axr[2 * g + 1];
          }
          acc[mi][j][r] += d;
        }
      }
    }
  }
  // ---- store ----
  unsigned short* outb = (unsigned short*)outv;
  float* outf = (float*)outv;
  #pragma unroll
  for (int mi = 0; mi < 4; ++mi) {
    #pragma unroll
    for (int r = 0; r < 4; ++r) {
      const size_t t = t0 + wr + mi * 16 + rr + r;
      #pragma unroll
      for (int j = 0; j < 4; ++j) {
        const int o = o0 + wc + j * 16 + c;
        const float v = acc[mi][j][r] + bv[j];
        const size_t oi = t * NOUT + o;
        if (isb) outb[oi] = f2b(v); else outf[oi] = v;
      }
    }
  }
}

extern "C" void kernel_launch(void* const* d_in, const int* in_sizes, int n_in,
                              void* d_out, int out_size, void* d_ws, size_t ws_size,
                              hipStream_t stream) {
  const void* x  = d_in[0];
  const void* w  = d_in[1];
  const void* bs = d_in[2];
  const void* la = d_in[3];
  const void* lb = d_in[4];
  const int*  ix = (const int*)d_in[5];

  const size_t xb_bytes = (size_t)NTOK * HID * 2;
  const size_t wb_bytes = (size_t)NOUT * HID * 2;
  const size_t ax1      = (size_t)NTOK * 256 * 4;   // one k-slice

  char* ws = (char*)d_ws;
  int nks, full;
  unsigned short *xb, *wb2;
  float* axp;
  if (ws_size >= xb_bytes + wb_bytes + 8 * ax1 + 64) {
    nks = 8; full = 1;
    xb = (unsigned short*)ws;
    wb2 = (unsigned short*)(ws + xb_bytes);
    axp = (float*)(ws + xb_bytes + wb_bytes);
  } else if (ws_size >= xb_bytes + wb_bytes + 2 * ax1 + 64) {
    nks = 2; full = 1;
    xb = (unsigned short*)ws;
    wb2 = (unsigned short*)(ws + xb_bytes);
    axp = (float*)(ws + xb_bytes + wb_bytes);
  } else {
    nks = 2; full = 0;                 // assume raw already bf16
    xb = (unsigned short*)x;
    wb2 = (unsigned short*)w;
    axp = (float*)ws;
  }

  prep_kernel<<<32 * nks + 2048, 256, 0, stream>>>(
      x, w, la, xb, wb2, axp, nks, full);
  gemm_kernel<<<256, 512, 0, stream>>>(
      x, w, xb, wb2, bs, lb, axp, ix, nks, d_out);
}